// Round 2
// baseline (1178.488 us; speedup 1.0000x reference)
//
#include <hip/hip_runtime.h>
#include <hip/hip_bf16.h>
#include <stdint.h>

#define N_PTS 32768
#define DIM   512
#define M_PROT 4096

typedef __attribute__((ext_vector_type(8))) short s16x8;
typedef __attribute__((ext_vector_type(4))) float f32x4;

__device__ __forceinline__ void async16(const void* g, void* l) {
  __builtin_amdgcn_global_load_lds(
      (const __attribute__((address_space(1))) void*)g,
      (__attribute__((address_space(3))) void*)l, 16, 0, 0);
}

__device__ __forceinline__ short bfbits(float f) {
  __hip_bfloat16 h = __float2bfloat16(f);
  return *reinterpret_cast<short*>(&h);
}

// ---------------------------------------------------------------------------
// K0: convert x and P rows to bf16, compute row squared norms.
// One wave per row of 512 floats; lane handles 8 elements.
// x bf16 goes into the blended region of d_out (scratch until K2 epilogue).
// ---------------------------------------------------------------------------
__global__ __launch_bounds__(64) void k0_prep(
    const float* __restrict__ x, const float* __restrict__ p,
    __hip_bfloat16* __restrict__ xb, __hip_bfloat16* __restrict__ pb,
    float* __restrict__ xsq, float* __restrict__ psq) {
  const int row = blockIdx.x;
  const int lane = threadIdx.x;
  const float* src;
  __hip_bfloat16* dst;
  if (row < N_PTS) { src = x + (size_t)row * DIM; dst = xb + (size_t)row * DIM; }
  else { src = p + (size_t)(row - N_PTS) * DIM; dst = pb + (size_t)(row - N_PTS) * DIM; }
  float4 v0 = *(const float4*)(src + lane * 8);
  float4 v1 = *(const float4*)(src + lane * 8 + 4);
  float s = v0.x*v0.x + v0.y*v0.y + v0.z*v0.z + v0.w*v0.w
          + v1.x*v1.x + v1.y*v1.y + v1.z*v1.z + v1.w*v1.w;
  union { s16x8 v; short e[8]; } cv;
  cv.e[0]=bfbits(v0.x); cv.e[1]=bfbits(v0.y); cv.e[2]=bfbits(v0.z); cv.e[3]=bfbits(v0.w);
  cv.e[4]=bfbits(v1.x); cv.e[5]=bfbits(v1.y); cv.e[6]=bfbits(v1.z); cv.e[7]=bfbits(v1.w);
  *reinterpret_cast<s16x8*>(dst + lane * 8) = cv.v;
  #pragma unroll
  for (int sft = 1; sft < 64; sft <<= 1) s += __shfl_xor(s, sft, 64);
  if (lane == 0) { if (row < N_PTS) xsq[row] = s; else psq[row - N_PTS] = s; }
}

// ---------------------------------------------------------------------------
// KT: P [M][D] f32 -> pT [D][M] bf16 (tiled transpose, 64x64 tiles).
// ---------------------------------------------------------------------------
__global__ __launch_bounds__(256) void kT(const float* __restrict__ p,
                                          __hip_bfloat16* __restrict__ pT) {
  __shared__ __hip_bfloat16 t[64][65];
  const int m0 = blockIdx.x * 64;
  const int d0 = blockIdx.y * 64;
  const int c = threadIdx.x & 63;
  const int r0 = threadIdx.x >> 6;
  #pragma unroll
  for (int i = 0; i < 16; ++i) {
    int r = r0 * 16 + i;
    t[c][r] = __float2bfloat16(p[(size_t)(m0 + r) * DIM + d0 + c]);
  }
  __syncthreads();
  #pragma unroll
  for (int i = 0; i < 16; ++i) {
    int r = r0 * 16 + i;
    pT[(size_t)(d0 + r) * M_PROT + m0 + c] = t[r][c];
  }
}

// ---------------------------------------------------------------------------
// K1: S = x @ P^T (bf16 MFMA, 128x128 tile, BK=64, K=512), fused epilogue:
// u = exp2(-sqrt(max(xsq+psq-2S,0)) * log2e/temp), store u (unnormalized) to
// the weights region, rowsum via 16-lane shuffle + atomicAdd.
// No max-subtraction needed: exponents stay within f32 normal range.
// ---------------------------------------------------------------------------
__global__ __launch_bounds__(256, 2) void k1_gemm_exp(
    const __hip_bfloat16* __restrict__ xb, const __hip_bfloat16* __restrict__ pb,
    const float* __restrict__ xsq, const float* __restrict__ psq,
    const float* __restrict__ temp_raw,
    float* __restrict__ uout, float* __restrict__ rowsum) {
  __shared__ __align__(16) short lsA[128 * 64];
  __shared__ __align__(16) short lsB[128 * 64];
  const int tid = threadIdx.x;
  const int lane = tid & 63;
  const int wave = tid >> 6;
  const int rb = blockIdx.x >> 5;   // 256 row blocks; consecutive blocks share x panel
  const int cb = blockIdx.x & 31;   // 32 col blocks
  const int wm = wave >> 1, wn = wave & 1;

  const char* gA = (const char*)(xb + (size_t)rb * 128 * DIM);
  const char* gB = (const char*)(pb + (size_t)cb * 128 * DIM);
  const int o0 = tid * 16;
  const int r0 = o0 >> 7;        // row within 32-row stripe per issue
  const int kb0 = o0 & 127;      // byte offset within 128B K-row

  f32x4 acc[4][4] = {};

  for (int kt = 0; kt < 8; ++kt) {
    __syncthreads();
    #pragma unroll
    for (int is = 0; is < 4; ++is) {
      int r = is * 32 + r0;
      async16(gA + (size_t)r * (DIM * 2) + kt * 128 + kb0,
              (char*)lsA + is * 4096 + wave * 1024);
      async16(gB + (size_t)r * (DIM * 2) + kt * 128 + kb0,
              (char*)lsB + is * 4096 + wave * 1024);
    }
    __syncthreads();
    #pragma unroll
    for (int kk = 0; kk < 2; ++kk) {
      s16x8 a[4], b[4];
      #pragma unroll
      for (int m = 0; m < 4; ++m)
        a[m] = *reinterpret_cast<const s16x8*>(
            &lsA[(wm * 64 + m * 16 + (lane & 15)) * 64 + kk * 32 + (lane >> 4) * 8]);
      #pragma unroll
      for (int n = 0; n < 4; ++n)
        b[n] = *reinterpret_cast<const s16x8*>(
            &lsB[(wn * 64 + n * 16 + (lane & 15)) * 64 + kk * 32 + (lane >> 4) * 8]);
      #pragma unroll
      for (int m = 0; m < 4; ++m)
        #pragma unroll
        for (int n = 0; n < 4; ++n)
          acc[m][n] = __builtin_amdgcn_mfma_f32_16x16x32_bf16(a[m], b[n], acc[m][n], 0, 0, 0);
    }
  }

  // epilogue
  const float traw = temp_raw[0];
  const float temp = (1.0f / (1.0f + __expf(-traw))) * 0.999f + 0.001f;
  const float c1 = 1.4426950408889634f / temp;  // log2(e)/temp

  const int rq = lane >> 4;
  const int cl = lane & 15;
  float ps[4];
  #pragma unroll
  for (int n = 0; n < 4; ++n) ps[n] = psq[cb * 128 + wn * 64 + n * 16 + cl];

  #pragma unroll
  for (int m = 0; m < 4; ++m) {
    #pragma unroll
    for (int r = 0; r < 4; ++r) {
      const int grow = rb * 128 + wm * 64 + m * 16 + rq * 4 + r;
      const float xs = xsq[grow];
      float rsum = 0.f;
      float* orow = uout + (size_t)grow * M_PROT + cb * 128 + wn * 64 + cl;
      #pragma unroll
      for (int n = 0; n < 4; ++n) {
        float s2 = xs + ps[n] - 2.0f * acc[m][n][r];
        float dd = sqrtf(fmaxf(s2, 0.f));
        float u = exp2f(-dd * c1);
        rsum += u;
        orow[n * 16] = u;
      }
      #pragma unroll
      for (int sft = 1; sft < 16; sft <<= 1) rsum += __shfl_xor(rsum, sft, 64);
      if (cl == 0) atomicAdd(&rowsum[grow], rsum);
    }
  }
}

// ---------------------------------------------------------------------------
// K2: blended = softmax-normalized weights @ P, computed as rinv ⊙ (u @ P)
// via out^T[d][n] = sum_m pT[d][m] * u[n][m]. Also writes normalized w back
// to the weights region in-place (each block owns its 64 rows exclusively).
// Block: 64 rows x full D=512; K=4096 streamed in 64-chunks.
// ---------------------------------------------------------------------------
__global__ __launch_bounds__(512, 4) void k2_norm_gemm(
    const __hip_bfloat16* __restrict__ pT,
    const float* __restrict__ rowsum,
    float* __restrict__ uw, float* __restrict__ blended) {
  __shared__ __align__(16) short lsA[512 * 64];  // pT chunk [512 d][64 m], 64 KB
  __shared__ __align__(16) short lsU[64 * 64];   // u chunk [64 n][64 m], 8 KB
  const int tid = threadIdx.x;
  const int lane = tid & 63;
  const int wave = tid >> 6;
  const int nb = blockIdx.x;
  const int wd = wave >> 1, wn = wave & 1;

  const int sn = tid >> 3;        // staging row n (0..63)
  const int sm = (tid & 7) * 8;   // staging m offset
  const float rinvS = 1.0f / rowsum[nb * 64 + sn];
  float* uRow = uw + (size_t)(nb * 64 + sn) * M_PROT + sm;

  const char* gA = (const char*)pT;
  const int o0 = tid * 16;
  const int d0s = o0 >> 7;        // d within 64-row stripe per issue
  const int mb0 = o0 & 127;

  f32x4 acc[8][2] = {};

  for (int mt = 0; mt < 64; ++mt) {
    __syncthreads();
    #pragma unroll
    for (int is = 0; is < 8; ++is) {
      int d = is * 64 + d0s;
      async16(gA + (size_t)d * (M_PROT * 2) + mt * 128 + mb0,
              (char*)lsA + is * 8192 + wave * 1024);
    }
    // stage u: read f32, write normalized w in-place, convert to bf16 -> LDS
    float4 u0 = *(const float4*)(uRow + mt * 64);
    float4 u1 = *(const float4*)(uRow + mt * 64 + 4);
    float4 w0, w1;
    w0.x = u0.x * rinvS; w0.y = u0.y * rinvS; w0.z = u0.z * rinvS; w0.w = u0.w * rinvS;
    w1.x = u1.x * rinvS; w1.y = u1.y * rinvS; w1.z = u1.z * rinvS; w1.w = u1.w * rinvS;
    *(float4*)(uRow + mt * 64) = w0;
    *(float4*)(uRow + mt * 64 + 4) = w1;
    union { s16x8 v; short e[8]; } cv;
    cv.e[0]=bfbits(u0.x); cv.e[1]=bfbits(u0.y); cv.e[2]=bfbits(u0.z); cv.e[3]=bfbits(u0.w);
    cv.e[4]=bfbits(u1.x); cv.e[5]=bfbits(u1.y); cv.e[6]=bfbits(u1.z); cv.e[7]=bfbits(u1.w);
    *reinterpret_cast<s16x8*>(&lsU[sn * 64 + sm]) = cv.v;
    __syncthreads();
    #pragma unroll
    for (int kk = 0; kk < 2; ++kk) {
      s16x8 b[2];
      #pragma unroll
      for (int n = 0; n < 2; ++n)
        b[n] = *reinterpret_cast<const s16x8*>(
            &lsU[(wn * 32 + n * 16 + (lane & 15)) * 64 + kk * 32 + (lane >> 4) * 8]);
      #pragma unroll
      for (int fd = 0; fd < 8; ++fd) {
        s16x8 a = *reinterpret_cast<const s16x8*>(
            &lsA[(wd * 128 + fd * 16 + (lane & 15)) * 64 + kk * 32 + (lane >> 4) * 8]);
        #pragma unroll
        for (int n = 0; n < 2; ++n)
          acc[fd][n] = __builtin_amdgcn_mfma_f32_16x16x32_bf16(a, b[n], acc[fd][n], 0, 0, 0);
      }
    }
  }

  // epilogue: out^T element (d, n): col = lane&15 -> n, row = (lane>>4)*4+reg -> d
  const int rq = lane >> 4, cl = lane & 15;
  #pragma unroll
  for (int n = 0; n < 2; ++n) {
    const int gn = nb * 64 + wn * 32 + n * 16 + cl;
    const float rv = 1.0f / rowsum[gn];
    #pragma unroll
    for (int fd = 0; fd < 8; ++fd) {
      const int dd = wd * 128 + fd * 16 + rq * 4;
      float4 o;
      o.x = acc[fd][n][0] * rv; o.y = acc[fd][n][1] * rv;
      o.z = acc[fd][n][2] * rv; o.w = acc[fd][n][3] * rv;
      *(float4*)(blended + (size_t)gn * DIM + dd) = o;
    }
  }
}

// ---------------------------------------------------------------------------
extern "C" void kernel_launch(void* const* d_in, const int* in_sizes, int n_in,
                              void* d_out, int out_size, void* d_ws, size_t ws_size,
                              hipStream_t stream) {
  const float* x    = (const float*)d_in[0];
  const float* p    = (const float*)d_in[1];
  const float* traw = (const float*)d_in[2];

  float* blended = (float*)d_out;                          // [N][D]
  float* weights = (float*)d_out + (size_t)N_PTS * DIM;    // [N][M]

  // xb (32 MB) aliases the blended region of d_out: K1 reads it; K2 writes
  // blended only in its epilogue (after K1 completed on the stream).
  __hip_bfloat16* xb = (__hip_bfloat16*)d_out;

  char* ws = (char*)d_ws;
  __hip_bfloat16* pb = (__hip_bfloat16*)(ws);               // 4 MB  [M][D]
  __hip_bfloat16* pT = (__hip_bfloat16*)(ws + 4194304);     // 4 MB  [D][M]
  float* xsq   = (float*)(ws + 8388608);                    // 128 KB
  float* psq   = (float*)(ws + 8519680);                    // 16 KB
  float* rowsum= (float*)(ws + 8536064);                    // 128 KB (total ~8.3 MB)

  hipMemsetAsync(rowsum, 0, N_PTS * sizeof(float), stream);
  k0_prep<<<N_PTS + M_PROT, 64, 0, stream>>>(x, p, xb, pb, xsq, psq);
  kT<<<dim3(M_PROT / 64, DIM / 64), 256, 0, stream>>>(p, pT);
  k1_gemm_exp<<<(N_PTS / 128) * (M_PROT / 128), 256, 0, stream>>>(
      xb, pb, xsq, psq, traw, weights, rowsum);
  k2_norm_gemm<<<N_PTS / 64, 512, 0, stream>>>(pT, rowsum, weights, blended);
}